// Round 11
// baseline (223.570 us; speedup 1.0000x reference)
//
#include <hip/hip_runtime.h>
#include <hip/hip_fp16.h>

// GCN 2-layer forward, CSR-gather with fixed-capacity radix binning.
// Bucket = dst >> 8  (391 buckets x 256 nodes), fixed region of CAP_B slots.
//   k_zeroB: zero bucket counters
//   k_binA : scatter packed records (src<<8 | dstLocal) into bucket regions
//   k_binB : per-bucket CSR build in LDS -> esrc (in-place), start, cnt, dinv
//   k_xw   : xws = f16((x @ W1) * dinv)   [4-way k-split, 2 nodes/thread,
//                                          XOR-swizzled W1 LDS]
//   k_gather1 : h = relu(b1 + dinv*(sum xws[src] + xws[i]));  hsc = f16(h*dinv)
//   k_gather2h: out = b2 + dinv*((sum hsc[src] + hsc[i]) @ W2)   [fused W2]
// f16 tables: 3.2 MB each -> fit per-XCD L2; gather bytes halve.
// d_out = [out (N*32) | h (N*16)]

#define NN 100000
#define NE 3200000
#define FIN 512
#define HID 16
#define NCLS 32
#define NB 391          // ceil(NN/256)
#define NBP 512         // padded bucket slots
#define CAP_B 9216      // fixed slots per bucket (mean 8184, +11 sigma)

// workspace element offsets (4-byte units)
#define OFF_BCNT  0                     // int [NBP]
#define OFF_START (NBP)                 // int [NN]
#define OFF_CNT   (NBP + NN)            // int [NN]
#define OFF_DINV  (NBP + 2*NN)          // float [NN]
#define OFF_EP    (NBP + 3*NN)          // u32 [NB*CAP_B]; becomes esrc
#define OFF_XWS   (OFF_EP + NB*CAP_B)   // half [NN*16] = NN*8 words
#define OFF_HSC   (OFF_XWS + NN*8)      // half [NN*16] = NN*8 words

__global__ __launch_bounds__(512) void k_zeroB(int* __restrict__ bcnt) {
    bcnt[threadIdx.x] = 0;
}

// Bin edges into fixed-cap bucket regions. 512 thr/block, 16 edges/thread.
__global__ __launch_bounds__(512) void k_binA(const int* __restrict__ src,
                                              const int* __restrict__ dst,
                                              int* __restrict__ bcnt,
                                              unsigned* __restrict__ ep) {
    __shared__ int hist[NBP];
    __shared__ int gpos[NBP];
    int tid = threadIdx.x;
    hist[tid] = 0;
    __syncthreads();
    int base = blockIdx.x * 8192;
    unsigned rec[16];
    int meta[16];                       // (p_local << 9) | bucket, or -1
#pragma unroll
    for (int k = 0; k < 16; ++k) {
        int e = base + tid + k * 512;
        if (e < NE) {
            int s = __builtin_nontemporal_load(src + e);
            int d = __builtin_nontemporal_load(dst + e);
            int b = d >> 8;
            int p = atomicAdd(&hist[b], 1);
            rec[k] = ((unsigned)s << 8) | (unsigned)(d & 255);
            meta[k] = (p << 9) | b;
        } else meta[k] = -1;
    }
    __syncthreads();
    int v = hist[tid];
    if (v > 0) gpos[tid] = atomicAdd(&bcnt[tid], v);   // direct reservation
    __syncthreads();
#pragma unroll
    for (int k = 0; k < 16; ++k) {
        if (meta[k] >= 0) {
            int b = meta[k] & 511;
            int p = meta[k] >> 9;
            ep[b * CAP_B + gpos[b] + p] = rec[k];
        }
    }
}

// Per-bucket CSR build in LDS. Block b owns nodes [b*256, b*256+256).
__global__ __launch_bounds__(256) void k_binB(unsigned* __restrict__ ep,
                                              const int* __restrict__ bcnt,
                                              int* __restrict__ startA,
                                              int* __restrict__ cntA,
                                              float* __restrict__ dinv) {
    __shared__ int nh[256];
    __shared__ int ns[256];
    __shared__ int np_[256];
    __shared__ int esL[CAP_B];
    int tid = threadIdx.x;
    int b = blockIdx.x;
    int gbase = b * CAP_B;
    int bc = bcnt[b];
    if (bc > CAP_B) bc = CAP_B;         // defensive clamp
    nh[tid] = 0;
    __syncthreads();
    for (int t = tid; t < bc; t += 256)
        atomicAdd(&nh[ep[gbase + t] & 255], 1);
    __syncthreads();
    int v = nh[tid];
    ns[tid] = v;
    __syncthreads();
#pragma unroll
    for (int o = 1; o < 256; o <<= 1) {
        int u = (tid >= o) ? ns[tid - o] : 0;
        __syncthreads();
        ns[tid] += u;
        __syncthreads();
    }
    int ex = ns[tid] - v;               // exclusive start within bucket
    np_[tid] = ex;
    __syncthreads();
    for (int t = tid; t < bc; t += 256) {
        unsigned r = ep[gbase + t];
        int dl = r & 255;
        int p = atomicAdd(&np_[dl], 1);
        esL[p] = (int)(r >> 8);
    }
    __syncthreads();
    for (int t = tid; t < bc; t += 256)
        ep[gbase + t] = (unsigned)esL[t];   // in-place: ep becomes esrc
    int node = b * 256 + tid;
    if (node < NN) {
        startA[node] = gbase + ex;
        cntA[node]   = v;
        dinv[node]   = rsqrtf((float)(v + 1));
    }
}

// GEMM1: 4-way k-split, 2 nodes per thread; XOR-swizzled W1 in LDS.
// Output converted to f16 (32 B/node).
__global__ __launch_bounds__(256) void k_xw(const float* __restrict__ x,
                                            const float* __restrict__ W1,
                                            const float* __restrict__ dinv,
                                            __half* __restrict__ xws) {
    __shared__ float w1[FIN * HID];     // 32 KB, XOR-swizzled float4 blocks
    for (int t = threadIdx.x; t < FIN * HID; t += 256) {
        int k = t >> 4, j = t & 15;
        int s = (k * 4 + ((j >> 2) ^ ((k >> 2) & 3))) * 4 + (j & 3);
        w1[s] = W1[t];
    }
    __syncthreads();
    int w  = threadIdx.x >> 6;          // wave in block (0..3)
    int nl = (threadIdx.x >> 2) & 15;   // node slot
    int c  = threadIdx.x & 3;           // k-split group
    int n0 = blockIdx.x * 128 + w * 32 + nl;
    int n1 = n0 + 16;
    bool v0 = n0 < NN, v1 = n1 < NN;
    const float4* x4 = reinterpret_cast<const float4*>(x);
    const float4* r0 = x4 + (v0 ? (size_t)n0 * (FIN / 4) : 0);
    const float4* r1 = x4 + (v1 ? (size_t)n1 * (FIN / 4) : 0);
    const float4* wv = reinterpret_cast<const float4*>(w1);
    float a0[HID], a1[HID];
#pragma unroll
    for (int j = 0; j < HID; ++j) { a0[j] = 0.f; a1[j] = 0.f; }
#pragma unroll 4
    for (int t = 0; t < 32; ++t) {
        int qk = c + 4 * t;             // float4-quad index into the row
        float4 xv0 = r0[qk];
        float4 xv1 = r1[qk];
        const float4* wb = wv + qk * 16;
#pragma unroll
        for (int e = 0; e < 4; ++e) {
            float xe0 = (e == 0) ? xv0.x : (e == 1) ? xv0.y : (e == 2) ? xv0.z : xv0.w;
            float xe1 = (e == 0) ? xv1.x : (e == 1) ? xv1.y : (e == 2) ? xv1.z : xv1.w;
#pragma unroll
            for (int j4 = 0; j4 < 4; ++j4) {
                float4 w4 = wb[e * 4 + (j4 ^ c)];   // true w1[k][j4*4..+3]
                a0[j4 * 4 + 0] += xe0 * w4.x;
                a0[j4 * 4 + 1] += xe0 * w4.y;
                a0[j4 * 4 + 2] += xe0 * w4.z;
                a0[j4 * 4 + 3] += xe0 * w4.w;
                a1[j4 * 4 + 0] += xe1 * w4.x;
                a1[j4 * 4 + 1] += xe1 * w4.y;
                a1[j4 * 4 + 2] += xe1 * w4.z;
                a1[j4 * 4 + 3] += xe1 * w4.w;
            }
        }
    }
#pragma unroll
    for (int j = 0; j < HID; ++j) {
        a0[j] += __shfl_xor(a0[j], 1);
        a0[j] += __shfl_xor(a0[j], 2);
        a1[j] += __shfl_xor(a1[j], 1);
        a1[j] += __shfl_xor(a1[j], 2);
    }
    if (c == 0) {
        if (v0) {
            float dv = dinv[n0];
            __half2 hv[8];
#pragma unroll
            for (int k = 0; k < 8; ++k)
                hv[k] = __floats2half2_rn(a0[2 * k] * dv, a0[2 * k + 1] * dv);
            float4* o = reinterpret_cast<float4*>(xws + (size_t)n0 * HID);
            o[0] = *reinterpret_cast<float4*>(&hv[0]);
            o[1] = *reinterpret_cast<float4*>(&hv[4]);
        }
        if (v1) {
            float dv = dinv[n1];
            __half2 hv[8];
#pragma unroll
            for (int k = 0; k < 8; ++k)
                hv[k] = __floats2half2_rn(a1[2 * k] * dv, a1[2 * k + 1] * dv);
            float4* o = reinterpret_cast<float4*>(xws + (size_t)n1 * HID);
            o[0] = *reinterpret_cast<float4*>(&hv[0]);
            o[1] = *reinterpret_cast<float4*>(&hv[4]);
        }
    }
}

// Gather layer 1: 1 node/wave, j = lane&15, 4-way edge parallel (c = lane>>4).
// MLP-4 unroll over f16 table. Writes h (d_out, f32) and hsc = f16(h*dinv).
__global__ __launch_bounds__(256) void k_gather1(const int* __restrict__ startA,
                                                 const int* __restrict__ cntA,
                                                 const int* __restrict__ esrc,
                                                 const __half* __restrict__ xws,
                                                 const float* __restrict__ dinv,
                                                 const float* __restrict__ b1,
                                                 float* __restrict__ hout,
                                                 __half* __restrict__ hsc) {
    int wave = (blockIdx.x * 256 + threadIdx.x) >> 6;
    if (wave >= NN) return;
    int i = wave;
    int lane = threadIdx.x & 63;
    int j = lane & 15;
    int c = lane >> 4;                  // 0..3
    int st = startA[i], en = st + cntA[i];
    float s0 = 0.f, s1 = 0.f, s2 = 0.f, s3 = 0.f;
    int e = st + c;
    for (; e + 12 < en; e += 16) {      // 16 edges/iter wave-wide, 4 per c-group
        int a0 = __builtin_nontemporal_load(esrc + e);
        int a1 = __builtin_nontemporal_load(esrc + e + 4);
        int a2 = __builtin_nontemporal_load(esrc + e + 8);
        int a3 = __builtin_nontemporal_load(esrc + e + 12);
        s0 += __half2float(xws[a0 * HID + j]);
        s1 += __half2float(xws[a1 * HID + j]);
        s2 += __half2float(xws[a2 * HID + j]);
        s3 += __half2float(xws[a3 * HID + j]);
    }
    for (; e < en; e += 4) s0 += __half2float(xws[esrc[e] * HID + j]);
    float sum = (s0 + s1) + (s2 + s3);
    sum += __shfl_xor(sum, 16);
    sum += __shfl_xor(sum, 32);
    if (c == 0) {
        float dv = dinv[i];
        float v = b1[j] + dv * (sum + __half2float(xws[i * HID + j]));
        float hv = v > 0.f ? v : 0.f;
        hout[i * HID + j] = hv;
        hsc[i * HID + j] = __float2half(hv * dv);
    }
}

// Gather layer 2 with fused W2: 1 node/wave, j = lane&15, 4-way edge parallel.
// Gathers f16 hsc, reduces, then epilogue:
//   out[i][jo] = b2[jo] + dinv[i] * sum_k v[k] * W2[k][jo]
__global__ __launch_bounds__(256) void k_gather2h(const int* __restrict__ startA,
                                                  const int* __restrict__ cntA,
                                                  const int* __restrict__ esrc,
                                                  const __half* __restrict__ hsc,
                                                  const float* __restrict__ dinv,
                                                  const float* __restrict__ W2,
                                                  const float* __restrict__ b2,
                                                  float* __restrict__ out) {
    __shared__ float w2s[HID * NCLS];
    __shared__ float b2s[NCLS];
    for (int t = threadIdx.x; t < HID * NCLS; t += 256) w2s[t] = W2[t];
    if (threadIdx.x < NCLS) b2s[threadIdx.x] = b2[threadIdx.x];
    __syncthreads();
    int wave = (blockIdx.x * 256 + threadIdx.x) >> 6;
    if (wave >= NN) return;
    int i = wave;
    int lane = threadIdx.x & 63;
    int j = lane & 15;
    int c = lane >> 4;                  // 0..3
    int st = startA[i], en = st + cntA[i];
    float s0 = 0.f, s1 = 0.f, s2 = 0.f, s3 = 0.f;
    int e = st + c;
    for (; e + 12 < en; e += 16) {      // 16 edges/iter wave-wide, 4 per c-group
        int a0 = __builtin_nontemporal_load(esrc + e);
        int a1 = __builtin_nontemporal_load(esrc + e + 4);
        int a2 = __builtin_nontemporal_load(esrc + e + 8);
        int a3 = __builtin_nontemporal_load(esrc + e + 12);
        s0 += __half2float(hsc[a0 * HID + j]);
        s1 += __half2float(hsc[a1 * HID + j]);
        s2 += __half2float(hsc[a2 * HID + j]);
        s3 += __half2float(hsc[a3 * HID + j]);
    }
    for (; e < en; e += 4) s0 += __half2float(hsc[esrc[e] * HID + j]);
    float sum = (s0 + s1) + (s2 + s3);
    sum += __shfl_xor(sum, 16);
    sum += __shfl_xor(sum, 32);
    sum += __half2float(hsc[i * HID + j]);   // self-loop term
    // epilogue: out[jo] for jo = lane (lanes 0..31)
    int jo = lane & 31;
    float acc = 0.f;
#pragma unroll
    for (int k = 0; k < HID; ++k) {
        float vk = __shfl(sum, k);      // v[k] broadcast (readlane)
        acc += vk * w2s[k * NCLS + jo];
    }
    if (lane < 32)
        out[i * NCLS + jo] = b2s[jo] + dinv[i] * acc;
}

extern "C" void kernel_launch(void* const* d_in, const int* in_sizes, int n_in,
                              void* d_out, int out_size, void* d_ws, size_t ws_size,
                              hipStream_t stream) {
    const float* x  = (const float*)d_in[0];
    const int* ei   = (const int*)d_in[1];      // [2][NE]
    const float* W1 = (const float*)d_in[2];
    const float* b1 = (const float*)d_in[3];
    const float* W2 = (const float*)d_in[4];
    const float* b2 = (const float*)d_in[5];

    const int* src = ei;
    const int* dst = ei + NE;

    int* wsi = (int*)d_ws;
    int*      bcnt  = wsi + OFF_BCNT;
    int*      startA= wsi + OFF_START;
    int*      cntA  = wsi + OFF_CNT;
    float*    dinv  = (float*)(wsi + OFF_DINV);
    unsigned* ep    = (unsigned*)(wsi + OFF_EP);   // packed, then esrc
    __half*   xws   = (__half*)(wsi + OFF_XWS);
    __half*   hsc   = (__half*)(wsi + OFF_HSC);

    float* outp = (float*)d_out;           // [NN*32]
    float* hout = outp + NN * NCLS;        // [NN*16]

    const int B = 256;

    hipLaunchKernelGGL(k_zeroB, dim3(1), dim3(512), 0, stream, bcnt);
    hipLaunchKernelGGL(k_binA,  dim3((NE + 8191) / 8192), dim3(512), 0, stream, src, dst, bcnt, ep);
    hipLaunchKernelGGL(k_binB,  dim3(NB), dim3(B), 0, stream, ep, bcnt, startA, cntA, dinv);
    hipLaunchKernelGGL(k_xw,    dim3((NN + 127) / 128), dim3(B), 0, stream, x, W1, dinv, xws);
    hipLaunchKernelGGL(k_gather1, dim3((NN * 64 + B - 1) / B), dim3(B), 0, stream,
                       startA, cntA, (const int*)ep, xws, dinv, b1, hout, hsc);
    hipLaunchKernelGGL(k_gather2h, dim3((NN * 64 + B - 1) / B), dim3(B), 0, stream,
                       startA, cntA, (const int*)ep, hsc, dinv, W2, b2, outp);
}

// Round 12
// 209.951 us; speedup vs baseline: 1.0649x; 1.0649x over previous
//
#include <hip/hip_runtime.h>
#include <hip/hip_fp16.h>

// GCN 2-layer forward, CSR-gather with fixed-capacity radix binning.
// Bucket = dst >> 8  (391 buckets x 256 nodes), fixed region of CAP_B slots.
//   k_zeroB: zero bucket counters
//   k_binA : scatter packed records (src<<8 | dstLocal); 782 blocks (3/CU)
//   k_binB : per-bucket CSR build in LDS -> esrc (in-place), start, cnt, dinv
//   k_xw   : xws = f16((x @ W1) * dinv)
//   k_gather1 : MLP-8 clamped gather; h, hsc = f16(h*dinv)
//   k_gather2h: MLP-8 clamped gather over hsc; fused W2 epilogue
// d_out = [out (N*32) | h (N*16)]

#define NN 100000
#define NE 3200000
#define FIN 512
#define HID 16
#define NCLS 32
#define NB 391          // ceil(NN/256)
#define NBP 512         // padded bucket slots
#define CAP_B 9216      // fixed slots per bucket (mean 8184, +11 sigma)

// workspace element offsets (4-byte units)
#define OFF_BCNT  0                     // int [NBP]
#define OFF_START (NBP)                 // int [NN]
#define OFF_CNT   (NBP + NN)            // int [NN]
#define OFF_DINV  (NBP + 2*NN)          // float [NN]
#define OFF_EP    (NBP + 3*NN)          // u32 [NB*CAP_B]; becomes esrc
#define OFF_XWS   (OFF_EP + NB*CAP_B)   // half [NN*16] = NN*8 words
#define OFF_HSC   (OFF_XWS + NN*8)      // half [NN*16] = NN*8 words

__global__ __launch_bounds__(512) void k_zeroB(int* __restrict__ bcnt) {
    bcnt[threadIdx.x] = 0;
}

// Bin edges into fixed-cap bucket regions. 512 thr/block, 8 edges/thread,
// 4096 edges/block, 782 blocks (~3/CU).
__global__ __launch_bounds__(512) void k_binA(const int* __restrict__ src,
                                              const int* __restrict__ dst,
                                              int* __restrict__ bcnt,
                                              unsigned* __restrict__ ep) {
    __shared__ int hist[NBP];
    __shared__ int gpos[NBP];
    int tid = threadIdx.x;
    hist[tid] = 0;
    __syncthreads();
    int base = blockIdx.x * 4096;
    unsigned rec[8];
    int meta[8];                        // (p_local << 9) | bucket, or -1
#pragma unroll
    for (int k = 0; k < 8; ++k) {
        int e = base + tid + k * 512;
        if (e < NE) {
            int s = __builtin_nontemporal_load(src + e);
            int d = __builtin_nontemporal_load(dst + e);
            int b = d >> 8;
            int p = atomicAdd(&hist[b], 1);
            rec[k] = ((unsigned)s << 8) | (unsigned)(d & 255);
            meta[k] = (p << 9) | b;
        } else meta[k] = -1;
    }
    __syncthreads();
    int v = hist[tid];
    if (v > 0) gpos[tid] = atomicAdd(&bcnt[tid], v);   // direct reservation
    __syncthreads();
#pragma unroll
    for (int k = 0; k < 8; ++k) {
        if (meta[k] >= 0) {
            int b = meta[k] & 511;
            int p = meta[k] >> 9;
            ep[b * CAP_B + gpos[b] + p] = rec[k];
        }
    }
}

// Per-bucket CSR build in LDS. Block b owns nodes [b*256, b*256+256).
__global__ __launch_bounds__(256) void k_binB(unsigned* __restrict__ ep,
                                              const int* __restrict__ bcnt,
                                              int* __restrict__ startA,
                                              int* __restrict__ cntA,
                                              float* __restrict__ dinv) {
    __shared__ int nh[256];
    __shared__ int ns[256];
    __shared__ int np_[256];
    __shared__ int esL[CAP_B];
    int tid = threadIdx.x;
    int b = blockIdx.x;
    int gbase = b * CAP_B;
    int bc = bcnt[b];
    if (bc > CAP_B) bc = CAP_B;         // defensive clamp
    nh[tid] = 0;
    __syncthreads();
    for (int t = tid; t < bc; t += 256)
        atomicAdd(&nh[ep[gbase + t] & 255], 1);
    __syncthreads();
    int v = nh[tid];
    ns[tid] = v;
    __syncthreads();
#pragma unroll
    for (int o = 1; o < 256; o <<= 1) {
        int u = (tid >= o) ? ns[tid - o] : 0;
        __syncthreads();
        ns[tid] += u;
        __syncthreads();
    }
    int ex = ns[tid] - v;               // exclusive start within bucket
    np_[tid] = ex;
    __syncthreads();
    for (int t = tid; t < bc; t += 256) {
        unsigned r = ep[gbase + t];
        int dl = r & 255;
        int p = atomicAdd(&np_[dl], 1);
        esL[p] = (int)(r >> 8);
    }
    __syncthreads();
    for (int t = tid; t < bc; t += 256)
        ep[gbase + t] = (unsigned)esL[t];   // in-place: ep becomes esrc
    int node = b * 256 + tid;
    if (node < NN) {
        startA[node] = gbase + ex;
        cntA[node]   = v;
        dinv[node]   = rsqrtf((float)(v + 1));
    }
}

// GEMM1: 4-way k-split, 2 nodes per thread; XOR-swizzled W1 in LDS; f16 out.
__global__ __launch_bounds__(256) void k_xw(const float* __restrict__ x,
                                            const float* __restrict__ W1,
                                            const float* __restrict__ dinv,
                                            __half* __restrict__ xws) {
    __shared__ float w1[FIN * HID];     // 32 KB, XOR-swizzled float4 blocks
    for (int t = threadIdx.x; t < FIN * HID; t += 256) {
        int k = t >> 4, j = t & 15;
        int s = (k * 4 + ((j >> 2) ^ ((k >> 2) & 3))) * 4 + (j & 3);
        w1[s] = W1[t];
    }
    __syncthreads();
    int w  = threadIdx.x >> 6;          // wave in block (0..3)
    int nl = (threadIdx.x >> 2) & 15;   // node slot
    int c  = threadIdx.x & 3;           // k-split group
    int n0 = blockIdx.x * 128 + w * 32 + nl;
    int n1 = n0 + 16;
    bool v0 = n0 < NN, v1 = n1 < NN;
    const float4* x4 = reinterpret_cast<const float4*>(x);
    const float4* r0 = x4 + (v0 ? (size_t)n0 * (FIN / 4) : 0);
    const float4* r1 = x4 + (v1 ? (size_t)n1 * (FIN / 4) : 0);
    const float4* wv = reinterpret_cast<const float4*>(w1);
    float a0[HID], a1[HID];
#pragma unroll
    for (int j = 0; j < HID; ++j) { a0[j] = 0.f; a1[j] = 0.f; }
#pragma unroll 4
    for (int t = 0; t < 32; ++t) {
        int qk = c + 4 * t;             // float4-quad index into the row
        float4 xv0 = r0[qk];
        float4 xv1 = r1[qk];
        const float4* wb = wv + qk * 16;
#pragma unroll
        for (int e = 0; e < 4; ++e) {
            float xe0 = (e == 0) ? xv0.x : (e == 1) ? xv0.y : (e == 2) ? xv0.z : xv0.w;
            float xe1 = (e == 0) ? xv1.x : (e == 1) ? xv1.y : (e == 2) ? xv1.z : xv1.w;
#pragma unroll
            for (int j4 = 0; j4 < 4; ++j4) {
                float4 w4 = wb[e * 4 + (j4 ^ c)];   // true w1[k][j4*4..+3]
                a0[j4 * 4 + 0] += xe0 * w4.x;
                a0[j4 * 4 + 1] += xe0 * w4.y;
                a0[j4 * 4 + 2] += xe0 * w4.z;
                a0[j4 * 4 + 3] += xe0 * w4.w;
                a1[j4 * 4 + 0] += xe1 * w4.x;
                a1[j4 * 4 + 1] += xe1 * w4.y;
                a1[j4 * 4 + 2] += xe1 * w4.z;
                a1[j4 * 4 + 3] += xe1 * w4.w;
            }
        }
    }
#pragma unroll
    for (int j = 0; j < HID; ++j) {
        a0[j] += __shfl_xor(a0[j], 1);
        a0[j] += __shfl_xor(a0[j], 2);
        a1[j] += __shfl_xor(a1[j], 1);
        a1[j] += __shfl_xor(a1[j], 2);
    }
    if (c == 0) {
        if (v0) {
            float dv = dinv[n0];
            __half2 hv[8];
#pragma unroll
            for (int k = 0; k < 8; ++k)
                hv[k] = __floats2half2_rn(a0[2 * k] * dv, a0[2 * k + 1] * dv);
            float4* o = reinterpret_cast<float4*>(xws + (size_t)n0 * HID);
            o[0] = *reinterpret_cast<float4*>(&hv[0]);
            o[1] = *reinterpret_cast<float4*>(&hv[4]);
        }
        if (v1) {
            float dv = dinv[n1];
            __half2 hv[8];
#pragma unroll
            for (int k = 0; k < 8; ++k)
                hv[k] = __floats2half2_rn(a1[2 * k] * dv, a1[2 * k + 1] * dv);
            float4* o = reinterpret_cast<float4*>(xws + (size_t)n1 * HID);
            o[0] = *reinterpret_cast<float4*>(&hv[0]);
            o[1] = *reinterpret_cast<float4*>(&hv[4]);
        }
    }
}

// Gather layer 1: 1 node/wave, j = lane&15, c = lane>>4 (4-way edge split).
// MLP-8 with branchless clamped tail: 32 edges in flight per round; a typical
// degree-32 node finishes in ONE memory-latency round.
__global__ __launch_bounds__(256) void k_gather1(const int* __restrict__ startA,
                                                 const int* __restrict__ cntA,
                                                 const int* __restrict__ esrc,
                                                 const __half* __restrict__ xws,
                                                 const float* __restrict__ dinv,
                                                 const float* __restrict__ b1,
                                                 float* __restrict__ hout,
                                                 __half* __restrict__ hsc) {
    int wave = (blockIdx.x * 256 + threadIdx.x) >> 6;
    if (wave >= NN) return;
    int i = wave;
    int lane = threadIdx.x & 63;
    int j = lane & 15;
    int c = lane >> 4;                  // 0..3
    int st = startA[i], en = st + cntA[i];
    float s[8];
#pragma unroll
    for (int k = 0; k < 8; ++k) s[k] = 0.f;
    for (int e = st + c; e < en; e += 32) {
        int a[8];
#pragma unroll
        for (int k = 0; k < 8; ++k) {
            int ee = e + 4 * k;
            a[k] = __builtin_nontemporal_load(esrc + (ee < en ? ee : e));
        }
#pragma unroll
        for (int k = 0; k < 8; ++k) {
            float v = __half2float(xws[a[k] * HID + j]);
            s[k] += (e + 4 * k < en) ? v : 0.f;
        }
    }
    float sum = ((s[0] + s[1]) + (s[2] + s[3])) + ((s[4] + s[5]) + (s[6] + s[7]));
    sum += __shfl_xor(sum, 16);
    sum += __shfl_xor(sum, 32);
    if (c == 0) {
        float dv = dinv[i];
        float v = b1[j] + dv * (sum + __half2float(xws[i * HID + j]));
        float hv = v > 0.f ? v : 0.f;
        hout[i * HID + j] = hv;
        hsc[i * HID + j] = __float2half(hv * dv);
    }
}

// Gather layer 2 with fused W2: same MLP-8 clamped structure over hsc.
__global__ __launch_bounds__(256) void k_gather2h(const int* __restrict__ startA,
                                                  const int* __restrict__ cntA,
                                                  const int* __restrict__ esrc,
                                                  const __half* __restrict__ hsc,
                                                  const float* __restrict__ dinv,
                                                  const float* __restrict__ W2,
                                                  const float* __restrict__ b2,
                                                  float* __restrict__ out) {
    __shared__ float w2s[HID * NCLS];
    __shared__ float b2s[NCLS];
    for (int t = threadIdx.x; t < HID * NCLS; t += 256) w2s[t] = W2[t];
    if (threadIdx.x < NCLS) b2s[threadIdx.x] = b2[threadIdx.x];
    __syncthreads();
    int wave = (blockIdx.x * 256 + threadIdx.x) >> 6;
    if (wave >= NN) return;
    int i = wave;
    int lane = threadIdx.x & 63;
    int j = lane & 15;
    int c = lane >> 4;                  // 0..3
    int st = startA[i], en = st + cntA[i];
    float s[8];
#pragma unroll
    for (int k = 0; k < 8; ++k) s[k] = 0.f;
    for (int e = st + c; e < en; e += 32) {
        int a[8];
#pragma unroll
        for (int k = 0; k < 8; ++k) {
            int ee = e + 4 * k;
            a[k] = __builtin_nontemporal_load(esrc + (ee < en ? ee : e));
        }
#pragma unroll
        for (int k = 0; k < 8; ++k) {
            float v = __half2float(hsc[a[k] * HID + j]);
            s[k] += (e + 4 * k < en) ? v : 0.f;
        }
    }
    float sum = ((s[0] + s[1]) + (s[2] + s[3])) + ((s[4] + s[5]) + (s[6] + s[7]));
    sum += __shfl_xor(sum, 16);
    sum += __shfl_xor(sum, 32);
    sum += __half2float(hsc[i * HID + j]);   // self-loop term
    // epilogue: out[jo] for jo = lane (lanes 0..31)
    int jo = lane & 31;
    float acc = 0.f;
#pragma unroll
    for (int k = 0; k < HID; ++k) {
        float vk = __shfl(sum, k);      // v[k] broadcast (readlane)
        acc += vk * w2s[k * NCLS + jo];
    }
    if (lane < 32)
        out[i * NCLS + jo] = b2s[jo] + dinv[i] * acc;
}

extern "C" void kernel_launch(void* const* d_in, const int* in_sizes, int n_in,
                              void* d_out, int out_size, void* d_ws, size_t ws_size,
                              hipStream_t stream) {
    const float* x  = (const float*)d_in[0];
    const int* ei   = (const int*)d_in[1];      // [2][NE]
    const float* W1 = (const float*)d_in[2];
    const float* b1 = (const float*)d_in[3];
    const float* W2 = (const float*)d_in[4];
    const float* b2 = (const float*)d_in[5];

    const int* src = ei;
    const int* dst = ei + NE;

    int* wsi = (int*)d_ws;
    int*      bcnt  = wsi + OFF_BCNT;
    int*      startA= wsi + OFF_START;
    int*      cntA  = wsi + OFF_CNT;
    float*    dinv  = (float*)(wsi + OFF_DINV);
    unsigned* ep    = (unsigned*)(wsi + OFF_EP);   // packed, then esrc
    __half*   xws   = (__half*)(wsi + OFF_XWS);
    __half*   hsc   = (__half*)(wsi + OFF_HSC);

    float* outp = (float*)d_out;           // [NN*32]
    float* hout = outp + NN * NCLS;        // [NN*16]

    const int B = 256;

    hipLaunchKernelGGL(k_zeroB, dim3(1), dim3(512), 0, stream, bcnt);
    hipLaunchKernelGGL(k_binA,  dim3((NE + 4095) / 4096), dim3(512), 0, stream, src, dst, bcnt, ep);
    hipLaunchKernelGGL(k_binB,  dim3(NB), dim3(B), 0, stream, ep, bcnt, startA, cntA, dinv);
    hipLaunchKernelGGL(k_xw,    dim3((NN + 127) / 128), dim3(B), 0, stream, x, W1, dinv, xws);
    hipLaunchKernelGGL(k_gather1, dim3((NN * 64 + B - 1) / B), dim3(B), 0, stream,
                       startA, cntA, (const int*)ep, xws, dinv, b1, hout, hsc);
    hipLaunchKernelGGL(k_gather2h, dim3((NN * 64 + B - 1) / B), dim3(B), 0, stream,
                       startA, cntA, (const int*)ep, hsc, dinv, W2, b2, outp);
}

// Round 13
// 202.692 us; speedup vs baseline: 1.1030x; 1.0358x over previous
//
#include <hip/hip_runtime.h>
#include <hip/hip_fp16.h>

// GCN 2-layer forward, CSR-gather with fixed-capacity radix binning.
// Bucket = dst >> 8  (391 buckets x 256 nodes), fixed region of CAP_B slots.
//   (memset) : zero bucket counters
//   k_binA   : scatter packed records (src<<8 | dstLocal); 782 blocks (3/CU)
//   k_binB   : per-bucket CSR build in LDS -> esrc (in-place), start, cnt, dinv
//   k_xw     : xws = f16((x @ W1) * dinv)
//   k_gather1 : half2 gather (8-way edge split, MLP-8); h, hsc = f16(h*dinv)
//   k_gather2h: half2 gather over hsc; fused W2 epilogue
// d_out = [out (N*32) | h (N*16)]

#define NN 100000
#define NE 3200000
#define FIN 512
#define HID 16
#define NCLS 32
#define NB 391          // ceil(NN/256)
#define NBP 512         // padded bucket slots
#define CAP_B 9216      // fixed slots per bucket (mean 8184, +11 sigma)

// workspace element offsets (4-byte units)
#define OFF_BCNT  0                     // int [NBP]
#define OFF_START (NBP)                 // int [NN]
#define OFF_CNT   (NBP + NN)            // int [NN]
#define OFF_DINV  (NBP + 2*NN)          // float [NN]
#define OFF_EP    (NBP + 3*NN)          // u32 [NB*CAP_B]; becomes esrc
#define OFF_XWS   (OFF_EP + NB*CAP_B)   // half [NN*16] = NN*8 words
#define OFF_HSC   (OFF_XWS + NN*8)      // half [NN*16] = NN*8 words

// Bin edges into fixed-cap bucket regions. 512 thr/block, 8 edges/thread,
// 4096 edges/block, 782 blocks (~3/CU).
__global__ __launch_bounds__(512) void k_binA(const int* __restrict__ src,
                                              const int* __restrict__ dst,
                                              int* __restrict__ bcnt,
                                              unsigned* __restrict__ ep) {
    __shared__ int hist[NBP];
    __shared__ int gpos[NBP];
    int tid = threadIdx.x;
    hist[tid] = 0;
    __syncthreads();
    int base = blockIdx.x * 4096;
    unsigned rec[8];
    int meta[8];                        // (p_local << 9) | bucket, or -1
#pragma unroll
    for (int k = 0; k < 8; ++k) {
        int e = base + tid + k * 512;
        if (e < NE) {
            int s = __builtin_nontemporal_load(src + e);
            int d = __builtin_nontemporal_load(dst + e);
            int b = d >> 8;
            int p = atomicAdd(&hist[b], 1);
            rec[k] = ((unsigned)s << 8) | (unsigned)(d & 255);
            meta[k] = (p << 9) | b;
        } else meta[k] = -1;
    }
    __syncthreads();
    int v = hist[tid];
    if (v > 0) gpos[tid] = atomicAdd(&bcnt[tid], v);   // direct reservation
    __syncthreads();
#pragma unroll
    for (int k = 0; k < 8; ++k) {
        if (meta[k] >= 0) {
            int b = meta[k] & 511;
            int p = meta[k] >> 9;
            ep[b * CAP_B + gpos[b] + p] = rec[k];
        }
    }
}

// Per-bucket CSR build in LDS. Block b owns nodes [b*256, b*256+256).
__global__ __launch_bounds__(256) void k_binB(unsigned* __restrict__ ep,
                                              const int* __restrict__ bcnt,
                                              int* __restrict__ startA,
                                              int* __restrict__ cntA,
                                              float* __restrict__ dinv) {
    __shared__ int nh[256];
    __shared__ int ns[256];
    __shared__ int np_[256];
    __shared__ int esL[CAP_B];
    int tid = threadIdx.x;
    int b = blockIdx.x;
    int gbase = b * CAP_B;
    int bc = bcnt[b];
    if (bc > CAP_B) bc = CAP_B;         // defensive clamp
    nh[tid] = 0;
    __syncthreads();
    for (int t = tid; t < bc; t += 256)
        atomicAdd(&nh[ep[gbase + t] & 255], 1);
    __syncthreads();
    int v = nh[tid];
    ns[tid] = v;
    __syncthreads();
#pragma unroll
    for (int o = 1; o < 256; o <<= 1) {
        int u = (tid >= o) ? ns[tid - o] : 0;
        __syncthreads();
        ns[tid] += u;
        __syncthreads();
    }
    int ex = ns[tid] - v;               // exclusive start within bucket
    np_[tid] = ex;
    __syncthreads();
    for (int t = tid; t < bc; t += 256) {
        unsigned r = ep[gbase + t];
        int dl = r & 255;
        int p = atomicAdd(&np_[dl], 1);
        esL[p] = (int)(r >> 8);
    }
    __syncthreads();
    for (int t = tid; t < bc; t += 256)
        ep[gbase + t] = (unsigned)esL[t];   // in-place: ep becomes esrc
    int node = b * 256 + tid;
    if (node < NN) {
        startA[node] = gbase + ex;
        cntA[node]   = v;
        dinv[node]   = rsqrtf((float)(v + 1));
    }
}

// GEMM1: 4-way k-split, 2 nodes per thread; XOR-swizzled W1 in LDS; f16 out.
__global__ __launch_bounds__(256) void k_xw(const float* __restrict__ x,
                                            const float* __restrict__ W1,
                                            const float* __restrict__ dinv,
                                            __half* __restrict__ xws) {
    __shared__ float w1[FIN * HID];     // 32 KB, XOR-swizzled float4 blocks
    for (int t = threadIdx.x; t < FIN * HID; t += 256) {
        int k = t >> 4, j = t & 15;
        int s = (k * 4 + ((j >> 2) ^ ((k >> 2) & 3))) * 4 + (j & 3);
        w1[s] = W1[t];
    }
    __syncthreads();
    int w  = threadIdx.x >> 6;          // wave in block (0..3)
    int nl = (threadIdx.x >> 2) & 15;   // node slot
    int c  = threadIdx.x & 3;           // k-split group
    int n0 = blockIdx.x * 128 + w * 32 + nl;
    int n1 = n0 + 16;
    bool v0 = n0 < NN, v1 = n1 < NN;
    const float4* x4 = reinterpret_cast<const float4*>(x);
    const float4* r0 = x4 + (v0 ? (size_t)n0 * (FIN / 4) : 0);
    const float4* r1 = x4 + (v1 ? (size_t)n1 * (FIN / 4) : 0);
    const float4* wv = reinterpret_cast<const float4*>(w1);
    float a0[HID], a1[HID];
#pragma unroll
    for (int j = 0; j < HID; ++j) { a0[j] = 0.f; a1[j] = 0.f; }
#pragma unroll 4
    for (int t = 0; t < 32; ++t) {
        int qk = c + 4 * t;             // float4-quad index into the row
        float4 xv0 = r0[qk];
        float4 xv1 = r1[qk];
        const float4* wb = wv + qk * 16;
#pragma unroll
        for (int e = 0; e < 4; ++e) {
            float xe0 = (e == 0) ? xv0.x : (e == 1) ? xv0.y : (e == 2) ? xv0.z : xv0.w;
            float xe1 = (e == 0) ? xv1.x : (e == 1) ? xv1.y : (e == 2) ? xv1.z : xv1.w;
#pragma unroll
            for (int j4 = 0; j4 < 4; ++j4) {
                float4 w4 = wb[e * 4 + (j4 ^ c)];   // true w1[k][j4*4..+3]
                a0[j4 * 4 + 0] += xe0 * w4.x;
                a0[j4 * 4 + 1] += xe0 * w4.y;
                a0[j4 * 4 + 2] += xe0 * w4.z;
                a0[j4 * 4 + 3] += xe0 * w4.w;
                a1[j4 * 4 + 0] += xe1 * w4.x;
                a1[j4 * 4 + 1] += xe1 * w4.y;
                a1[j4 * 4 + 2] += xe1 * w4.z;
                a1[j4 * 4 + 3] += xe1 * w4.w;
            }
        }
    }
#pragma unroll
    for (int j = 0; j < HID; ++j) {
        a0[j] += __shfl_xor(a0[j], 1);
        a0[j] += __shfl_xor(a0[j], 2);
        a1[j] += __shfl_xor(a1[j], 1);
        a1[j] += __shfl_xor(a1[j], 2);
    }
    if (c == 0) {
        if (v0) {
            float dv = dinv[n0];
            __half2 hv[8];
#pragma unroll
            for (int k = 0; k < 8; ++k)
                hv[k] = __floats2half2_rn(a0[2 * k] * dv, a0[2 * k + 1] * dv);
            float4* o = reinterpret_cast<float4*>(xws + (size_t)n0 * HID);
            o[0] = *reinterpret_cast<float4*>(&hv[0]);
            o[1] = *reinterpret_cast<float4*>(&hv[4]);
        }
        if (v1) {
            float dv = dinv[n1];
            __half2 hv[8];
#pragma unroll
            for (int k = 0; k < 8; ++k)
                hv[k] = __floats2half2_rn(a1[2 * k] * dv, a1[2 * k + 1] * dv);
            float4* o = reinterpret_cast<float4*>(xws + (size_t)n1 * HID);
            o[0] = *reinterpret_cast<float4*>(&hv[0]);
            o[1] = *reinterpret_cast<float4*>(&hv[4]);
        }
    }
}

// Gather layer 1: 1 node/wave. j2 = lane&7 (feature PAIR via __half2),
// c = lane>>3 (8-way edge split), MLP-8 -> 64 edges in flight per wave.
// f32 accumulation. Butterfly reduce over c (xor 8/16/32).
__global__ __launch_bounds__(256) void k_gather1(const int* __restrict__ startA,
                                                 const int* __restrict__ cntA,
                                                 const int* __restrict__ esrc,
                                                 const __half2* __restrict__ xws2,
                                                 const float* __restrict__ dinv,
                                                 const float* __restrict__ b1,
                                                 float* __restrict__ hout,
                                                 __half2* __restrict__ hsc2) {
    int wave = (blockIdx.x * 256 + threadIdx.x) >> 6;
    if (wave >= NN) return;
    int i = wave;
    int lane = threadIdx.x & 63;
    int j2 = lane & 7;
    int c = lane >> 3;                  // 0..7
    int st = startA[i], en = st + cntA[i];
    float sx[8], sy[8];
#pragma unroll
    for (int k = 0; k < 8; ++k) { sx[k] = 0.f; sy[k] = 0.f; }
    for (int e = st + c; e < en; e += 64) {
        int a[8];
#pragma unroll
        for (int k = 0; k < 8; ++k) {
            int ee = e + 8 * k;
            a[k] = __builtin_nontemporal_load(esrc + (ee < en ? ee : e));
        }
#pragma unroll
        for (int k = 0; k < 8; ++k) {
            float2 f = __half22float2(xws2[a[k] * 8 + j2]);
            bool ok = (e + 8 * k) < en;
            sx[k] += ok ? f.x : 0.f;
            sy[k] += ok ? f.y : 0.f;
        }
    }
    float sumx = ((sx[0] + sx[1]) + (sx[2] + sx[3])) + ((sx[4] + sx[5]) + (sx[6] + sx[7]));
    float sumy = ((sy[0] + sy[1]) + (sy[2] + sy[3])) + ((sy[4] + sy[5]) + (sy[6] + sy[7]));
    sumx += __shfl_xor(sumx, 8);  sumy += __shfl_xor(sumy, 8);
    sumx += __shfl_xor(sumx, 16); sumy += __shfl_xor(sumy, 16);
    sumx += __shfl_xor(sumx, 32); sumy += __shfl_xor(sumy, 32);
    if (c == 0) {
        float dv = dinv[i];
        float2 self = __half22float2(xws2[i * 8 + j2]);
        float vx = b1[2 * j2]     + dv * (sumx + self.x);
        float vy = b1[2 * j2 + 1] + dv * (sumy + self.y);
        float hx = vx > 0.f ? vx : 0.f;
        float hy = vy > 0.f ? vy : 0.f;
        *reinterpret_cast<float2*>(hout + i * HID + 2 * j2) = make_float2(hx, hy);
        hsc2[i * 8 + j2] = __floats2half2_rn(hx * dv, hy * dv);
    }
}

// Gather layer 2 with fused W2: same half2 MLP-8 structure over hsc.
// After butterfly every lane holds its j2-pair total; epilogue broadcasts
// the 8 pairs via readlane and multiplies against LDS-staged W2.
__global__ __launch_bounds__(256) void k_gather2h(const int* __restrict__ startA,
                                                  const int* __restrict__ cntA,
                                                  const int* __restrict__ esrc,
                                                  const __half2* __restrict__ hsc2,
                                                  const float* __restrict__ dinv,
                                                  const float* __restrict__ W2,
                                                  const float* __restrict__ b2,
                                                  float* __restrict__ out) {
    __shared__ float w2s[HID * NCLS];
    __shared__ float b2s[NCLS];
    for (int t = threadIdx.x; t < HID * NCLS; t += 256) w2s[t] = W2[t];
    if (threadIdx.x < NCLS) b2s[threadIdx.x] = b2[threadIdx.x];
    __syncthreads();
    int wave = (blockIdx.x * 256 + threadIdx.x) >> 6;
    if (wave >= NN) return;
    int i = wave;
    int lane = threadIdx.x & 63;
    int j2 = lane & 7;
    int c = lane >> 3;                  // 0..7
    int st = startA[i], en = st + cntA[i];
    float sx[8], sy[8];
#pragma unroll
    for (int k = 0; k < 8; ++k) { sx[k] = 0.f; sy[k] = 0.f; }
    for (int e = st + c; e < en; e += 64) {
        int a[8];
#pragma unroll
        for (int k = 0; k < 8; ++k) {
            int ee = e + 8 * k;
            a[k] = __builtin_nontemporal_load(esrc + (ee < en ? ee : e));
        }
#pragma unroll
        for (int k = 0; k < 8; ++k) {
            float2 f = __half22float2(hsc2[a[k] * 8 + j2]);
            bool ok = (e + 8 * k) < en;
            sx[k] += ok ? f.x : 0.f;
            sy[k] += ok ? f.y : 0.f;
        }
    }
    float sumx = ((sx[0] + sx[1]) + (sx[2] + sx[3])) + ((sx[4] + sx[5]) + (sx[6] + sx[7]));
    float sumy = ((sy[0] + sy[1]) + (sy[2] + sy[3])) + ((sy[4] + sy[5]) + (sy[6] + sy[7]));
    sumx += __shfl_xor(sumx, 8);  sumy += __shfl_xor(sumy, 8);
    sumx += __shfl_xor(sumx, 16); sumy += __shfl_xor(sumy, 16);
    sumx += __shfl_xor(sumx, 32); sumy += __shfl_xor(sumy, 32);
    {   // self-loop term (each lane adds its own j2 pair)
        float2 self = __half22float2(hsc2[i * 8 + j2]);
        sumx += self.x;
        sumy += self.y;
    }
    // epilogue: every lane has the total for ITS j2 pair; broadcast all 8.
    int jo = lane & 31;
    float acc = 0.f;
#pragma unroll
    for (int p = 0; p < 8; ++p) {
        acc += __shfl(sumx, p) * w2s[(2 * p) * NCLS + jo];
        acc += __shfl(sumy, p) * w2s[(2 * p + 1) * NCLS + jo];
    }
    if (lane < 32)
        out[i * NCLS + jo] = b2s[jo] + dinv[i] * acc;
}

extern "C" void kernel_launch(void* const* d_in, const int* in_sizes, int n_in,
                              void* d_out, int out_size, void* d_ws, size_t ws_size,
                              hipStream_t stream) {
    const float* x  = (const float*)d_in[0];
    const int* ei   = (const int*)d_in[1];      // [2][NE]
    const float* W1 = (const float*)d_in[2];
    const float* b1 = (const float*)d_in[3];
    const float* W2 = (const float*)d_in[4];
    const float* b2 = (const float*)d_in[5];

    const int* src = ei;
    const int* dst = ei + NE;

    int* wsi = (int*)d_ws;
    int*      bcnt  = wsi + OFF_BCNT;
    int*      startA= wsi + OFF_START;
    int*      cntA  = wsi + OFF_CNT;
    float*    dinv  = (float*)(wsi + OFF_DINV);
    unsigned* ep    = (unsigned*)(wsi + OFF_EP);   // packed, then esrc
    __half*   xws   = (__half*)(wsi + OFF_XWS);
    __half2*  xws2  = (__half2*)(wsi + OFF_XWS);
    __half2*  hsc2  = (__half2*)(wsi + OFF_HSC);

    float* outp = (float*)d_out;           // [NN*32]
    float* hout = outp + NN * NCLS;        // [NN*16]

    const int B = 256;

    hipMemsetAsync(bcnt, 0, NBP * sizeof(int), stream);
    hipLaunchKernelGGL(k_binA,  dim3((NE + 4095) / 4096), dim3(512), 0, stream, src, dst, bcnt, ep);
    hipLaunchKernelGGL(k_binB,  dim3(NB), dim3(B), 0, stream, ep, bcnt, startA, cntA, dinv);
    hipLaunchKernelGGL(k_xw,    dim3((NN + 127) / 128), dim3(B), 0, stream, x, W1, dinv, xws);
    hipLaunchKernelGGL(k_gather1, dim3((NN * 64 + B - 1) / B), dim3(B), 0, stream,
                       startA, cntA, (const int*)ep, xws2, dinv, b1, hout, hsc2);
    hipLaunchKernelGGL(k_gather2h, dim3((NN * 64 + B - 1) / B), dim3(B), 0, stream,
                       startA, cntA, (const int*)ep, hsc2, dinv, W2, b2, outp);
}